// Round 12
// baseline (1026.905 us; speedup 1.0000x reference)
//
#include <hip/hip_runtime.h>
#include <cstdint>
#include <cstddef>

// ---------------------------------------------------------------------------
// DockPointNet fused edge-MLP + segment-max, f16 MFMA + CSR counting sort.
// Round 12 = round 11 + VALU/addressing diet + deeper prefetch:
//   (1) strength-reduced frag addressing: swz block offset = ((4ks+g)^(c16&7))
//       is n-independent -> 22 weight-frag reads become 2 base addrs +
//       constant ds offsets (n*2048B). ~100 VALU/window removed.
//   (2) x-values prefetched one tile ahead (named float4 pair; consume-then-
//       overwrite ordering, no extra copies; unified regs ~120 < 128 cliff).
//   (3) walk uses wave-uniform __ballot boundary mask -> scalar branches;
//       geo loads as float3 (4 vec loads, not 12 scalar).
// r10/r11 profile: VALU 62% / MFMA 6.7 / DS ~15 / HBM 27 at 4 waves/SIMD
// (LDS+reg double-capped) -> cut VALU, pipeline deeper.
// ---------------------------------------------------------------------------

typedef _Float16 f16x8 __attribute__((ext_vector_type(8)));
typedef _Float16 f16x2 __attribute__((ext_vector_type(2)));
typedef float    f32x4 __attribute__((ext_vector_type(4)));
typedef float    f32x3 __attribute__((ext_vector_type(3)));

#define ENC_NEGINF 0x007FFFFFu   // fenc(-inf)
#define LDK 64                   // msg/W row stride (f16), swizzled
#define LDH 132                  // h2 row stride (f16)

__device__ __forceinline__ int swz(int row, int col) {
    return (col & 7) | ((((col >> 3) ^ row) & 7) << 3);
}

__device__ __forceinline__ unsigned fenc(float f) {
    unsigned u = __float_as_uint(f);
    return (u & 0x80000000u) ? ~u : (u | 0x80000000u);
}

__device__ __forceinline__ float fdec(unsigned k) {
    if (k == ENC_NEGINF) return 0.0f;
    unsigned u = (k & 0x80000000u) ? (k ^ 0x80000000u) : ~k;
    return __uint_as_float(u);
}

__device__ __forceinline__ f16x2 pkrtz(float a, float b) {
    auto p = __builtin_amdgcn_cvt_pkrtz(a, b);   // __fp16 ext_vector(2)
    return __builtin_bit_cast(f16x2, p);
}

__global__ void init_out_kernel(unsigned* __restrict__ out, int n4) {
    int i = blockIdx.x * blockDim.x + threadIdx.x;
    if (i < n4)
        ((uint4*)out)[i] = make_uint4(ENC_NEGINF, ENC_NEGINF, ENC_NEGINF, ENC_NEGINF);
}

__global__ void finalize_out_kernel(float* __restrict__ out, int n4) {
    int i = blockIdx.x * blockDim.x + threadIdx.x;
    if (i < n4) {
        uint4 k = ((const uint4*)out)[i];
        float4 r;
        r.x = fdec(k.x); r.y = fdec(k.y); r.z = fdec(k.z); r.w = fdec(k.w);
        ((float4*)out)[i] = r;
    }
}

// ---------------- CSR build ----------------
__global__ void hist_kernel(const int* __restrict__ dstI, int* __restrict__ counts, int E) {
    int i = blockIdx.x * blockDim.x + threadIdx.x;
    if (i < E) atomicAdd(&counts[dstI[i]], 1);
}

__global__ __launch_bounds__(1024) void scan_blk(const int* __restrict__ in,
                                                 int* __restrict__ outp,
                                                 int* __restrict__ bsums, int N) {
    __shared__ int wsum[16];
    const int tid = threadIdx.x, lane = tid & 63, wid = tid >> 6;
    int i = blockIdx.x * 1024 + tid;
    int v = (i < N) ? in[i] : 0;
    int incl = v;
#pragma unroll
    for (int m = 1; m < 64; m <<= 1) {
        int t = __shfl_up(incl, m, 64);
        if (lane >= m) incl += t;
    }
    if (lane == 63) wsum[wid] = incl;
    __syncthreads();
    int woff = 0;
#pragma unroll
    for (int k = 0; k < 16; ++k) woff += (k < wid) ? wsum[k] : 0;
    if (i < N) outp[i] = woff + incl - v;
    if (tid == 1023 && bsums != nullptr) bsums[blockIdx.x] = woff + incl;
}

// scatter with fused top-level offset (bsums already scanned).
__global__ void scatter_kernel(const int* __restrict__ srcI, const int* __restrict__ dstI,
                               int* __restrict__ nextp, const int* __restrict__ bsums,
                               int2* __restrict__ se, int* __restrict__ dst_g, int E) {
    int i = blockIdx.x * blockDim.x + threadIdx.x;
    if (i < E) {
        int d = dstI[i];
        int p = bsums[d >> 10] + atomicAdd(&nextp[d], 1);
        se[p] = make_int2(srcI[i], i);
        dst_g[p] = d;
    }
}

// ---------------- CSR edge kernel: 8 waves/block, 2-deep prefetch ---------
__global__ __launch_bounds__(512, 4) void edge_kernel_csr(
    const float* __restrict__ x,   const float* __restrict__ pos,
    const float* __restrict__ nrm, const float* __restrict__ ea,
    const float* __restrict__ W1,  const float* __restrict__ b1,
    const float* __restrict__ g1,  const float* __restrict__ be1,
    const float* __restrict__ W2,  const float* __restrict__ b2,
    const float* __restrict__ g2,  const float* __restrict__ be2,
    const int2* __restrict__ se,   const int* __restrict__ dst_g,
    unsigned* __restrict__ out, int E, int ntiles, int tilesPerBlock)
{
    __shared__ _Float16 W1t[48][LDK];     // 6.0 KB  (swizzled [n][k])
    __shared__ _Float16 W2t[128][LDK];    // 16.0 KB
    __shared__ _Float16 msgA[128][LDK];   // 16.0 KB (msg; h1 aliased after GEMM1)
    __shared__ _Float16 h2w[128][LDH];    // 33.0 KB
    __shared__ int dstL[128];

    const int lane = threadIdx.x & 63;
    const int w    = threadIdx.x >> 6;   // 0..7
    const int c16  = lane & 15;
    const int g    = lane >> 4;
    const int row0 = w * 16;

    // ---- stage weights (f16, transposed, zero-padded, swizzled) ----
    for (int i = threadIdx.x; i < 48 * 64; i += 512) {
        int n = i >> 6, k = i & 63;
        W1t[n][swz(n, k)] = (n < 47 && k < 47) ? (_Float16)W1[k * 47 + n] : (_Float16)0.f;
    }
    for (int i = threadIdx.x; i < 128 * 64; i += 512) {
        int n = i >> 6, k = i & 63;
        W2t[n][swz(n, k)] = (k < 47) ? (_Float16)W2[k * 128 + n] : (_Float16)0.f;
    }
    for (int i = threadIdx.x; i < 128 * LDK; i += 512)
        (&msgA[0][0])[i] = (_Float16)0.f;

    // ---- per-lane LN params ----
    float b1v[3], g1v[3], be1v[3];
#pragma unroll
    for (int n = 0; n < 3; ++n) {
        int cc = n * 16 + c16;
        bool vld = cc < 47;
        b1v[n]  = vld ? b1[cc]  : 0.f;
        g1v[n]  = vld ? g1[cc]  : 0.f;
        be1v[n] = vld ? be1[cc] : 0.f;
    }
    float b2v[8];
    f16x2 g2pk[4], be2pk[4];
#pragma unroll
    for (int n = 0; n < 8; ++n) b2v[n] = b2[n * 16 + c16];
#pragma unroll
    for (int h = 0; h < 4; ++h) {
        g2pk[h][0]  = (_Float16)g2[(2 * h) * 16 + c16];
        g2pk[h][1]  = (_Float16)g2[(2 * h + 1) * 16 + c16];
        be2pk[h][0] = (_Float16)be2[(2 * h) * 16 + c16];
        be2pk[h][1] = (_Float16)be2[(2 * h + 1) * 16 + c16];
    }
    __syncthreads();

    // gather lane roles
    const int xr = lane >> 2;            // x: row within wave's 16 edges
    const int xc = (lane & 3) * 8;       //    8 channels per lane
    const int eg = lane / 11, ec = lane - eg * 11;   // ea: lanes<44
    const bool ea_act  = lane < 44;
    const bool geo_act = lane < 48;

    // ---- hoisted fragment addressing (n-independent swizzle blocks) ----
    // swz(row, ks*32+g*8) block = ((4ks+g) ^ (row&7)); row&7 == c16&7 for all
    // rows we touch (row = m*16 + c16). Byte offset = block*16.
    const int x7   = c16 & 7;
    const int k0off = ((0 + g) ^ x7) * 16;          // ks=0
    const int k1off = ((4 + g) ^ x7) * 16;          // ks=1
    const char* aRow  = (const char*)&msgA[row0 + c16][0];
    const char* w1Row = (const char*)&W1t[c16][0];  // + n*2048
    const char* w2Row = (const char*)&W2t[c16][0];  // + n*2048

    const int tbeg = blockIdx.x * tilesPerBlock;
    int tend = tbeg + tilesPerBlock;
    if (tend > ntiles) tend = ntiles;
    if (tbeg >= tend) return;

    // ---- cross-tile prefetch state: NAMED SCALARS/VECS ONLY ----
    int    pf_sx = 0;
    int    pf_e0 = -1, pf_e1 = -1, pf_e2 = -1, pf_e3 = -1;
    int    pf_gs = 0,  pf_gd = -1;
    float  pf_ea0 = 0.f, pf_ea1 = 0.f, pf_ea2 = 0.f, pf_ea3 = 0.f;
    float4 pf_xa = make_float4(0.f, 0.f, 0.f, 0.f);
    float4 pf_xb = make_float4(0.f, 0.f, 0.f, 0.f);

    // prologue: level-1 indices + level-2 values for the first tile
    {
        const int b2 = tbeg * 128 + row0;
        int p = b2 + xr;
        pf_sx = (p < E) ? se[p].x : 0;
        if (ea_act) {
            int p0 = b2 + eg, p1 = b2 + 4 + eg, p2 = b2 + 8 + eg, p3 = b2 + 12 + eg;
            pf_e0 = (p0 < E) ? se[p0].y : -1;
            pf_e1 = (p1 < E) ? se[p1].y : -1;
            pf_e2 = (p2 < E) ? se[p2].y : -1;
            pf_e3 = (p3 < E) ? se[p3].y : -1;
        }
        if (geo_act) {
            int pg = b2 + c16;
            bool v = pg < E;
            pf_gs = v ? se[pg].x : 0;
            pf_gd = v ? dst_g[pg] : -1;
        }
        const float4* xp = (const float4*)(x + (pf_sx * 32 + xc));
        pf_xa = xp[0]; pf_xb = xp[1];
        if (ea_act) {
            pf_ea0 = (pf_e0 >= 0) ? ea[pf_e0 * 11 + ec] : 0.f;
            pf_ea1 = (pf_e1 >= 0) ? ea[pf_e1 * 11 + ec] : 0.f;
            pf_ea2 = (pf_e2 >= 0) ? ea[pf_e2 * 11 + ec] : 0.f;
            pf_ea3 = (pf_e3 >= 0) ? ea[pf_e3 * 11 + ec] : 0.f;
        }
    }

    for (int tile = tbeg; tile < tend; ++tile) {
        const int base = tile * 128 + row0;
        const bool more = (tile + 1 < tend);

        // ---- Phase 1: commit prefetched values + in-tile geo ----
        {
            bool vx = (base + xr) < E;
            {
                int r = row0 + xr;
                f16x8 hv;
                hv[0] = (_Float16)(vx ? pf_xa.x : 0.f); hv[1] = (_Float16)(vx ? pf_xa.y : 0.f);
                hv[2] = (_Float16)(vx ? pf_xa.z : 0.f); hv[3] = (_Float16)(vx ? pf_xa.w : 0.f);
                hv[4] = (_Float16)(vx ? pf_xb.x : 0.f); hv[5] = (_Float16)(vx ? pf_xb.y : 0.f);
                hv[6] = (_Float16)(vx ? pf_xb.z : 0.f); hv[7] = (_Float16)(vx ? pf_xb.w : 0.f);
                *(f16x8*)&msgA[r][swz(r, xc)] = hv;
            }
            if (ea_act) {
                int r0 = row0 + 0 * 4 + eg; msgA[r0][swz(r0, 36 + ec)] = (_Float16)pf_ea0;
                int r1 = row0 + 1 * 4 + eg; msgA[r1][swz(r1, 36 + ec)] = (_Float16)pf_ea1;
                int r2 = row0 + 2 * 4 + eg; msgA[r2][swz(r2, 36 + ec)] = (_Float16)pf_ea2;
                int r3 = row0 + 3 * 4 + eg; msgA[r3][swz(r3, 36 + ec)] = (_Float16)pf_ea3;
            }
            if (geo_act) {
                int d2 = (pf_gd < 0) ? 0 : pf_gd;
                f32x3 pi = *(const f32x3*)(pos + 3 * d2);
                f32x3 pj = *(const f32x3*)(pos + 3 * pf_gs);
                f32x3 ni = *(const f32x3*)(nrm + 3 * d2);
                f32x3 nj = *(const f32x3*)(nrm + 3 * pf_gs);
                int r = row0 + c16;
                float px = pj[0] - pi[0], py = pj[1] - pi[1], pz = pj[2] - pi[2];
                float v1x, v1y, v1z, v2x, v2y, v2z;
                if (g == 0)      { v1x = ni[0]; v1y = ni[1]; v1z = ni[2]; v2x = px;    v2y = py;    v2z = pz; }
                else if (g == 1) { v1x = nj[0]; v1y = nj[1]; v1z = nj[2]; v2x = px;    v2y = py;    v2z = pz; }
                else             { v1x = ni[0]; v1y = ni[1]; v1z = ni[2]; v2x = nj[0]; v2y = nj[1]; v2z = nj[2]; }
                float cx = v1y * v2z - v1z * v2y;
                float cy = v1z * v2x - v1x * v2z;
                float cz = v1x * v2y - v1y * v2x;
                float ang = atan2f(sqrtf(cx * cx + cy * cy + cz * cz),
                                   v1x * v2x + v1y * v2y + v1z * v2z);
                msgA[r][swz(r, 33 + g)] = (_Float16)ang;
                if (g == 0) {
                    msgA[r][swz(r, 32)] = (_Float16)sqrtf(px * px + py * py + pz * pz);
                    dstL[r] = pf_gd;
                }
            }
        }
        // no barrier: all LDS rows above are wave-private

        // issue level-1 prefetch for tile+1 (pf_* consumed above)
        if (more) {
            const int b2 = base + 128;
            int p = b2 + xr;
            pf_sx = (p < E) ? se[p].x : 0;
            if (ea_act) {
                int p0 = b2 + eg, p1 = b2 + 4 + eg, p2 = b2 + 8 + eg, p3 = b2 + 12 + eg;
                pf_e0 = (p0 < E) ? se[p0].y : -1;
                pf_e1 = (p1 < E) ? se[p1].y : -1;
                pf_e2 = (p2 < E) ? se[p2].y : -1;
                pf_e3 = (p3 < E) ? se[p3].y : -1;
            }
            if (geo_act) {
                int pg = b2 + c16;
                bool v = pg < E;
                pf_gs = v ? se[pg].x : 0;
                pf_gd = v ? dst_g[pg] : -1;
            }
        }

        // ---- Phase 2: GEMM1 (16x48) + LN1 -> h1 back into msgA ----
        f32x4 acc1[3];
#pragma unroll
        for (int n = 0; n < 3; ++n) acc1[n] = (f32x4){0.f, 0.f, 0.f, 0.f};
        {
            f16x8 a0 = *(const f16x8*)(aRow + k0off);
            f16x8 a1 = *(const f16x8*)(aRow + k1off);
#pragma unroll
            for (int n = 0; n < 3; ++n) {
                f16x8 b0 = *(const f16x8*)(w1Row + n * 2048 + k0off);
                f16x8 b1 = *(const f16x8*)(w1Row + n * 2048 + k1off);
                acc1[n] = __builtin_amdgcn_mfma_f32_16x16x32_f16(a0, b0, acc1[n], 0, 0, 0);
                acc1[n] = __builtin_amdgcn_mfma_f32_16x16x32_f16(a1, b1, acc1[n], 0, 0, 0);
            }
        }
#pragma unroll
        for (int q = 0; q < 4; ++q) {
            float t0 = fmaxf(acc1[0][q] + b1v[0], 0.f);
            float t1 = fmaxf(acc1[1][q] + b1v[1], 0.f);
            float t2 = fmaxf(acc1[2][q] + b1v[2], 0.f);   // col 47 -> 0
            float s = t0 + t1 + t2;
            float s2 = t0 * t0 + t1 * t1 + t2 * t2;
#pragma unroll
            for (int m = 1; m < 16; m <<= 1) {
                s  += __shfl_xor(s,  m, 64);
                s2 += __shfl_xor(s2, m, 64);
            }
            float mu  = s * (1.f / 47.f);
            float var = s2 * (1.f / 47.f) - mu * mu;
            float rs  = rsqrtf(var + 1e-5f);
            int r = row0 + 4 * g + q;
            msgA[r][swz(r, c16)]      = (_Float16)((t0 - mu) * rs * g1v[0] + be1v[0]);
            msgA[r][swz(r, 16 + c16)] = (_Float16)((t1 - mu) * rs * g1v[1] + be1v[1]);
            msgA[r][swz(r, 32 + c16)] = (_Float16)((t2 - mu) * rs * g1v[2] + be1v[2]);
        }

        // issue level-2 value prefetch for tile+1 (level-1 returned by now)
        if (more) {
            const float4* xp = (const float4*)(x + (pf_sx * 32 + xc));
            pf_xa = xp[0]; pf_xb = xp[1];
            if (ea_act) {
                pf_ea0 = (pf_e0 >= 0) ? ea[pf_e0 * 11 + ec] : 0.f;
                pf_ea1 = (pf_e1 >= 0) ? ea[pf_e1 * 11 + ec] : 0.f;
                pf_ea2 = (pf_e2 >= 0) ? ea[pf_e2 * 11 + ec] : 0.f;
                pf_ea3 = (pf_e3 >= 0) ? ea[pf_e3 * 11 + ec] : 0.f;
            }
        }

        // ---- Phase 3: GEMM2 (16x128) + LN2 (packed-f16 apply) -> h2w ----
        f32x4 acc2[8];
#pragma unroll
        for (int n = 0; n < 8; ++n) acc2[n] = (f32x4){0.f, 0.f, 0.f, 0.f};
        {
            f16x8 a0 = *(const f16x8*)(aRow + k0off);
            f16x8 a1 = *(const f16x8*)(aRow + k1off);
#pragma unroll
            for (int n = 0; n < 8; ++n) {
                f16x8 b0 = *(const f16x8*)(w2Row + n * 2048 + k0off);
                f16x8 b1 = *(const f16x8*)(w2Row + n * 2048 + k1off);
                acc2[n] = __builtin_amdgcn_mfma_f32_16x16x32_f16(a0, b0, acc2[n], 0, 0, 0);
                acc2[n] = __builtin_amdgcn_mfma_f32_16x16x32_f16(a1, b1, acc2[n], 0, 0, 0);
            }
        }
#pragma unroll
        for (int q = 0; q < 4; ++q) {
            float t[8];
            float s = 0.f, s2 = 0.f;
#pragma unroll
            for (int n = 0; n < 8; ++n) {
                t[n] = fmaxf(acc2[n][q] + b2v[n], 0.f);
                s += t[n]; s2 += t[n] * t[n];
            }
#pragma unroll
            for (int m = 1; m < 16; m <<= 1) {
                s  += __shfl_xor(s,  m, 64);
                s2 += __shfl_xor(s2, m, 64);
            }
            float mu  = s * (1.f / 128.f);
            float var = s2 * (1.f / 128.f) - mu * mu;
            float rs  = rsqrtf(var + 1e-5f);
            int r = row0 + 4 * g + q;
            f16x2 apk = pkrtz(rs, rs);
            f16x2 cpk = pkrtz(-mu * rs, -mu * rs);
#pragma unroll
            for (int h = 0; h < 4; ++h) {
                f16x2 tpk = pkrtz(t[2 * h], t[2 * h + 1]);
                f16x2 z   = tpk * apk + cpk;
                f16x2 hvp = z * g2pk[h] + be2pk[h];
                h2w[r][(2 * h) * 16 + c16]     = hvp[0];
                h2w[r][(2 * h + 1) * 16 + c16] = hvp[1];
            }
        }

        // ---- Phase 4: segmented max walk, scalar boundary mask ----
        {
            unsigned long long bmask;
            {
                int rr = lane & 15;
                int dc = dstL[row0 + rr];
                int dn = (rr < 15) ? dstL[row0 + rr + 1] : -2;
                bmask = __ballot(lane < 16 && dc != dn) | (1ull << 15);
            }
            f16x2 mneg; mneg[0] = mneg[1] = (_Float16)(-65504.f);
            f16x2 mx = mneg;
            int segStart = 0;
#pragma unroll
            for (int r = 0; r < 16; ++r) {
                f16x2 pk = *(const f16x2*)&h2w[row0 + r][lane * 2];
                mx[0] = (pk[0] > mx[0]) ? pk[0] : mx[0];
                mx[1] = (pk[1] > mx[1]) ? pk[1] : mx[1];
                if ((bmask >> r) & 1) {
                    int dcur = dstL[row0 + r];
                    if (dcur >= 0) {
                        unsigned e0 = fenc((float)mx[0]);
                        unsigned e1 = fenc((float)mx[1]);
                        unsigned* orow = out + (size_t)dcur * 128 + lane * 2;
                        if (segStart > 0 && r < 15) {
                            unsigned long long pk2 =
                                ((unsigned long long)e1 << 32) | (unsigned long long)e0;
                            *(unsigned long long*)orow = pk2;
                        } else {
                            atomicMax(orow,     e0);
                            atomicMax(orow + 1, e1);
                        }
                    }
                    mx = mneg;
                    segStart = r + 1;
                }
            }
        }
    }
}

// ---------------- fallback: direct atomics, no CSR (round-2 form) ----------------
#define LDKF 72
__global__ __launch_bounds__(256) void edge_kernel_atomic(
    const float* __restrict__ x,   const float* __restrict__ pos,
    const float* __restrict__ nrm, const float* __restrict__ ea,
    const float* __restrict__ W1,  const float* __restrict__ b1,
    const float* __restrict__ g1,  const float* __restrict__ be1,
    const float* __restrict__ W2,  const float* __restrict__ b2,
    const float* __restrict__ g2,  const float* __restrict__ be2,
    const int* __restrict__ srcI,  const int* __restrict__ dstI,
    unsigned* __restrict__ out, int E, int ntiles)
{
    __shared__ _Float16 W1t[48][LDKF];
    __shared__ _Float16 W2t[128][LDKF];
    __shared__ _Float16 msgA[64][LDKF];
    __shared__ int dst_s[64];

    const int lane = threadIdx.x & 63;
    const int w    = threadIdx.x >> 6;
    const int c16  = lane & 15;
    const int g    = lane >> 4;

    for (int i = threadIdx.x; i < 48 * 64; i += 256) {
        int n = i >> 6, k = i & 63;
        W1t[n][k] = (n < 47 && k < 47) ? (_Float16)W1[k * 47 + n] : (_Float16)0.f;
    }
    for (int i = threadIdx.x; i < 128 * 64; i += 256) {
        int n = i >> 6, k = i & 63;
        W2t[n][k] = (k < 47) ? (_Float16)W2[k * 128 + n] : (_Float16)0.f;
    }
    for (int i = threadIdx.x; i < 64 * LDKF; i += 256)
        (&msgA[0][0])[i] = (_Float16)0.f;

    float b1v[3], g1v[3], be1v[3];
#pragma unroll
    for (int n = 0; n < 3; ++n) {
        int cc = n * 16 + c16;
        bool vld = cc < 47;
        b1v[n]  = vld ? b1[cc]  : 0.f;
        g1v[n]  = vld ? g1[cc]  : 0.f;
        be1v[n] = vld ? be1[cc] : 0.f;
    }
    float b2v[8], g2v[8], be2v[8];
#pragma unroll
    for (int n = 0; n < 8; ++n) {
        int cc = n * 16 + c16;
        b2v[n] = b2[cc]; g2v[n] = g2[cc]; be2v[n] = be2[cc];
    }
    __syncthreads();

    for (int tile = blockIdx.x; tile < ntiles; tile += gridDim.x) {
        const int base = tile * 64 + w * 16;
        const int row0 = w * 16;
#pragma unroll
        for (int i = 0; i < 8; ++i) {
            int el = i * 2 + (lane >> 5);
            int e  = base + el;
            int c  = lane & 31;
            float v = 0.f;
            if (e < E) v = x[(size_t)srcI[e] * 32 + c];
            msgA[row0 + el][c] = (_Float16)v;
        }
        if (lane < 44) {
            int eg = lane / 11, c = lane - eg * 11;
#pragma unroll
            for (int i = 0; i < 4; ++i) {
                int el = i * 4 + eg;
                int e  = base + el;
                float v = 0.f;
                if (e < E) v = ea[(size_t)e * 11 + c];
                msgA[row0 + el][36 + c] = (_Float16)v;
            }
        }
        if (lane < 48) {
            int el = c16;
            int e  = base + el;
            int s = 0, d = 0;
            bool vld = e < E;
            if (vld) { s = srcI[e]; d = dstI[e]; }
            float pix = pos[d * 3 + 0], piy = pos[d * 3 + 1], piz = pos[d * 3 + 2];
            float pjx = pos[s * 3 + 0], pjy = pos[s * 3 + 1], pjz = pos[s * 3 + 2];
            float nix = nrm[d * 3 + 0], niy = nrm[d * 3 + 1], niz = nrm[d * 3 + 2];
            float njx = nrm[s * 3 + 0], njy = nrm[s * 3 + 1], njz = nrm[s * 3 + 2];
            float px = pjx - pix, py = pjy - piy, pz = pjz - piz;
            float v1x, v1y, v1z, v2x, v2y, v2z;
            if (g == 0)      { v1x = nix; v1y = niy; v1z = niz; v2x = px;  v2y = py;  v2z = pz;  }
            else if (g == 1) { v1x = njx; v1y = njy; v1z = njz; v2x = px;  v2y = py;  v2z = pz;  }
            else             { v1x = nix; v1y = niy; v1z = niz; v2x = njx; v2y = njy; v2z = njz; }
            float cx = v1y * v2z - v1z * v2y;
            float cy = v1z * v2x - v1x * v2z;
            float cz = v1x * v2y - v1y * v2x;
            float ang = atan2f(sqrtf(cx * cx + cy * cy + cz * cz),
                               v1x * v2x + v1y * v2y + v1z * v2z);
            msgA[row0 + el][33 + g] = (_Float16)ang;
            if (g == 0) {
                msgA[row0 + el][32] = (_Float16)sqrtf(px * px + py * py + pz * pz);
                dst_s[row0 + el] = vld ? d : -1;
            }
        }

        f32x4 acc1[3];
#pragma unroll
        for (int n = 0; n < 3; ++n) acc1[n] = (f32x4){0.f, 0.f, 0.f, 0.f};
#pragma unroll
        for (int ks = 0; ks < 2; ++ks) {
            f16x8 a = *(const f16x8*)&msgA[row0 + c16][ks * 32 + g * 8];
#pragma unroll
            for (int n = 0; n < 3; ++n) {
                f16x8 b = *(const f16x8*)&W1t[n * 16 + c16][ks * 32 + g * 8];
                acc1[n] = __builtin_amdgcn_mfma_f32_16x16x32_f16(a, b, acc1[n], 0, 0, 0);
            }
        }
#pragma unroll
        for (int q = 0; q < 4; ++q) {
            float t0 = fmaxf(acc1[0][q] + b1v[0], 0.f);
            float t1 = fmaxf(acc1[1][q] + b1v[1], 0.f);
            float t2 = fmaxf(acc1[2][q] + b1v[2], 0.f);
            float s = t0 + t1 + t2;
            float s2 = t0 * t0 + t1 * t1 + t2 * t2;
#pragma unroll
            for (int m = 1; m < 16; m <<= 1) {
                s  += __shfl_xor(s,  m, 64);
                s2 += __shfl_xor(s2, m, 64);
            }
            float mu  = s * (1.f / 47.f);
            float var = s2 * (1.f / 47.f) - mu * mu;
            float rs  = rsqrtf(var + 1e-5f);
            int r = row0 + 4 * g + q;
            msgA[r][c16]      = (_Float16)((t0 - mu) * rs * g1v[0] + be1v[0]);
            msgA[r][16 + c16] = (_Float16)((t1 - mu) * rs * g1v[1] + be1v[1]);
            msgA[r][32 + c16] = (_Float16)((t2 - mu) * rs * g1v[2] + be1v[2]);
        }

        f32x4 acc2[8];
#pragma unroll
        for (int n = 0; n < 8; ++n) acc2[n] = (f32x4){0.f, 0.f, 0.f, 0.f};
#pragma unroll
        for (int ks = 0; ks < 2; ++ks) {
            f16x8 a = *(const f16x8*)&msgA[row0 + c16][ks * 32 + g * 8];
#pragma unroll
            for (int n = 0; n < 8; ++n) {
                f16x8 b = *(const f16x8*)&W2t[n * 16 + c16][ks * 32 + g * 8];
                acc2[n] = __builtin_amdgcn_mfma_f32_16x16x32_f16(a, b, acc2[n], 0, 0, 0);
            }
        }
        int4 dd = *(const int4*)&dst_s[row0 + 4 * g];
#pragma unroll
        for (int q = 0; q < 4; ++q) {
            float t[8];
            float s = 0.f, s2 = 0.f;
#pragma unroll
            for (int n = 0; n < 8; ++n) {
                t[n] = fmaxf(acc2[n][q] + b2v[n], 0.f);
                s += t[n]; s2 += t[n] * t[n];
            }
#pragma unroll
            for (int m = 1; m < 16; m <<= 1) {
                s  += __shfl_xor(s,  m, 64);
                s2 += __shfl_xor(s2, m, 64);
            }
            float mu  = s * (1.f / 128.f);
            float var = s2 * (1.f / 128.f) - mu * mu;
            float rs  = rsqrtf(var + 1e-5f);
            int d = (&dd.x)[q];
            if (d >= 0) {
                unsigned* orow = out + (size_t)d * 128u;
#pragma unroll
                for (int n = 0; n < 8; ++n) {
                    float o = (t[n] - mu) * rs * g2v[n] + be2v[n];
                    atomicMax(orow + n * 16 + c16, fenc(o));
                }
            }
        }
    }
}

extern "C" void kernel_launch(void* const* d_in, const int* in_sizes, int n_in,
                              void* d_out, int out_size, void* d_ws, size_t ws_size,
                              hipStream_t stream) {
    const float* x   = (const float*)d_in[0];
    const float* pos = (const float*)d_in[1];
    const float* nrm = (const float*)d_in[2];
    const float* ea  = (const float*)d_in[3];
    const float* W1  = (const float*)d_in[4];
    const float* b1  = (const float*)d_in[5];
    const float* g1  = (const float*)d_in[6];
    const float* be1 = (const float*)d_in[7];
    const float* W2  = (const float*)d_in[8];
    const float* b2  = (const float*)d_in[9];
    const float* g2  = (const float*)d_in[10];
    const float* be2 = (const float*)d_in[11];
    const int*   idx = (const int*)d_in[12];

    const int N = in_sizes[0] / 32;
    const int E = in_sizes[3] / 11;
    const int* srcI = idx;
    const int* dstI = idx + E;

    unsigned* outU = (unsigned*)d_out;
    const int n = N * 128;

    init_out_kernel<<<(n / 4 + 255) / 256, 256, 0, stream>>>(outU, n / 4);

    const int nb = (N + 1023) / 1024;
    // ws layout: se[E] int2 | counts[N] | nextp[N] | dst_g[E] | bsums[nb]
    const size_t needed = (size_t)E * 8 + (size_t)(2LL * N + E + nb) * 4;

    if (ws_size >= needed) {
        int2* se     = (int2*)d_ws;
        int*  counts = (int*)(se + E);
        int*  nextp  = counts + N;
        int*  dst_g  = nextp + N;
        int*  bsums  = dst_g + E;

        hipMemsetAsync(counts, 0, (size_t)N * 4, stream);
        hist_kernel<<<(E + 255) / 256, 256, 0, stream>>>(dstI, counts, E);
        scan_blk<<<nb, 1024, 0, stream>>>(counts, nextp, bsums, N);
        scan_blk<<<1, 1024, 0, stream>>>(bsums, bsums, (int*)nullptr, nb);
        scatter_kernel<<<(E + 255) / 256, 256, 0, stream>>>(srcI, dstI, nextp, bsums,
                                                            se, dst_g, E);

        const int ntiles = (E + 127) / 128;
        int grid = ntiles < 512 ? ntiles : 512;    // 2 blocks/CU resident, persistent
        int tpb  = (ntiles + grid - 1) / grid;
        edge_kernel_csr<<<grid, 512, 0, stream>>>(x, pos, nrm, ea,
                                                  W1, b1, g1, be1,
                                                  W2, b2, g2, be2,
                                                  se, dst_g,
                                                  outU, E, ntiles, tpb);
    } else {
        const int ntiles = (E + 63) / 64;
        int grid = ntiles < 4096 ? ntiles : 4096;
        edge_kernel_atomic<<<grid, 256, 0, stream>>>(x, pos, nrm, ea,
                                                     W1, b1, g1, be1,
                                                     W2, b2, g2, be2,
                                                     srcI, dstI, outU, E, ntiles);
    }

    finalize_out_kernel<<<(n / 4 + 255) / 256, 256, 0, stream>>>((float*)d_out, n / 4);
}

// Round 13
// 815.420 us; speedup vs baseline: 1.2594x; 1.2594x over previous
//
#include <hip/hip_runtime.h>
#include <cstdint>
#include <cstddef>

// ---------------------------------------------------------------------------
// DockPointNet fused edge-MLP + segment-max, f16 MFMA + CSR counting sort.
// Round 13 = round 11 edge kernel VERBATIM (r12's bundled changes spilled:
// hbm_bytes 0.99->1.38 GB, reverted per abort criterion) + ONE side change:
// CSR record packed as int3{src,e,dst} in a single array -> scatter does one
// random line-touch per edge instead of two (se[] + dst_g[] in r11).
// Sides are ~380us of the 842us total; scatter is the dominant side cost.
// ---------------------------------------------------------------------------

typedef _Float16 f16x8 __attribute__((ext_vector_type(8)));
typedef _Float16 f16x2 __attribute__((ext_vector_type(2)));
typedef float    f32x4 __attribute__((ext_vector_type(4)));

#define ENC_NEGINF 0x007FFFFFu   // fenc(-inf)
#define LDK 64                   // msg/W row stride (f16), swizzled
#define LDH 132                  // h2 row stride (f16)

__device__ __forceinline__ int swz(int row, int col) {
    return (col & 7) | ((((col >> 3) ^ row) & 7) << 3);
}

__device__ __forceinline__ unsigned fenc(float f) {
    unsigned u = __float_as_uint(f);
    return (u & 0x80000000u) ? ~u : (u | 0x80000000u);
}

__device__ __forceinline__ float fdec(unsigned k) {
    if (k == ENC_NEGINF) return 0.0f;
    unsigned u = (k & 0x80000000u) ? (k ^ 0x80000000u) : ~k;
    return __uint_as_float(u);
}

__device__ __forceinline__ f16x2 pkrtz(float a, float b) {
    auto p = __builtin_amdgcn_cvt_pkrtz(a, b);   // __fp16 ext_vector(2)
    return __builtin_bit_cast(f16x2, p);
}

__global__ void init_out_kernel(unsigned* __restrict__ out, int n4) {
    int i = blockIdx.x * blockDim.x + threadIdx.x;
    if (i < n4)
        ((uint4*)out)[i] = make_uint4(ENC_NEGINF, ENC_NEGINF, ENC_NEGINF, ENC_NEGINF);
}

__global__ void finalize_out_kernel(float* __restrict__ out, int n4) {
    int i = blockIdx.x * blockDim.x + threadIdx.x;
    if (i < n4) {
        uint4 k = ((const uint4*)out)[i];
        float4 r;
        r.x = fdec(k.x); r.y = fdec(k.y); r.z = fdec(k.z); r.w = fdec(k.w);
        ((float4*)out)[i] = r;
    }
}

// ---------------- CSR build ----------------
__global__ void hist_kernel(const int* __restrict__ dstI, int* __restrict__ counts, int E) {
    int i = blockIdx.x * blockDim.x + threadIdx.x;
    if (i < E) atomicAdd(&counts[dstI[i]], 1);
}

// exclusive scan of one 1024-chunk per block; optional per-block totals.
__global__ __launch_bounds__(1024) void scan_blk(const int* __restrict__ in,
                                                 int* __restrict__ outp,
                                                 int* __restrict__ bsums, int N) {
    __shared__ int wsum[16];
    const int tid = threadIdx.x, lane = tid & 63, wid = tid >> 6;
    int i = blockIdx.x * 1024 + tid;
    int v = (i < N) ? in[i] : 0;
    int incl = v;
#pragma unroll
    for (int m = 1; m < 64; m <<= 1) {
        int t = __shfl_up(incl, m, 64);
        if (lane >= m) incl += t;
    }
    if (lane == 63) wsum[wid] = incl;
    __syncthreads();
    int woff = 0;
#pragma unroll
    for (int k = 0; k < 16; ++k) woff += (k < wid) ? wsum[k] : 0;
    if (i < N) outp[i] = woff + incl - v;
    if (tid == 1023 && bsums != nullptr) bsums[blockIdx.x] = woff + incl;
}

// scatter with fused top-level offset; packed int3 record = ONE random
// line-touch per edge (r11 wrote to two arrays = two line-touches).
__global__ void scatter_kernel(const int* __restrict__ srcI, const int* __restrict__ dstI,
                               int* __restrict__ nextp, const int* __restrict__ bsums,
                               int3* __restrict__ rec, int E) {
    int i = blockIdx.x * blockDim.x + threadIdx.x;
    if (i < E) {
        int d = dstI[i];
        int p = bsums[d >> 10] + atomicAdd(&nextp[d], 1);
        rec[p] = make_int3(srcI[i], i, d);
    }
}

// ---------------- CSR edge kernel: 8 waves/block, cross-tile prefetch ------
// (round-11 structure verbatim; se/dst_g replaced by the int3 record)
__global__ __launch_bounds__(512, 4) void edge_kernel_csr(
    const float* __restrict__ x,   const float* __restrict__ pos,
    const float* __restrict__ nrm, const float* __restrict__ ea,
    const float* __restrict__ W1,  const float* __restrict__ b1,
    const float* __restrict__ g1,  const float* __restrict__ be1,
    const float* __restrict__ W2,  const float* __restrict__ b2,
    const float* __restrict__ g2,  const float* __restrict__ be2,
    const int3* __restrict__ rec,
    unsigned* __restrict__ out, int E, int ntiles, int tilesPerBlock)
{
    __shared__ _Float16 W1t[48][LDK];     // 6.0 KB  (swizzled [n][k])
    __shared__ _Float16 W2t[128][LDK];    // 16.0 KB
    __shared__ _Float16 msgA[128][LDK];   // 16.0 KB (msg; h1 aliased after GEMM1)
    __shared__ _Float16 h2w[128][LDH];    // 33.0 KB (linear; walk is 2-way = free)
    __shared__ int dstL[128];

    const int lane = threadIdx.x & 63;
    const int w    = threadIdx.x >> 6;   // 0..7
    const int c16  = lane & 15;
    const int g    = lane >> 4;
    const int row0 = w * 16;

    // ---- stage weights (f16, transposed, zero-padded, swizzled) ----
    for (int i = threadIdx.x; i < 48 * 64; i += 512) {
        int n = i >> 6, k = i & 63;
        W1t[n][swz(n, k)] = (n < 47 && k < 47) ? (_Float16)W1[k * 47 + n] : (_Float16)0.f;
    }
    for (int i = threadIdx.x; i < 128 * 64; i += 512) {
        int n = i >> 6, k = i & 63;
        W2t[n][swz(n, k)] = (k < 47) ? (_Float16)W2[k * 128 + n] : (_Float16)0.f;
    }
    for (int i = threadIdx.x; i < 128 * LDK; i += 512)
        (&msgA[0][0])[i] = (_Float16)0.f;

    // ---- per-lane LN params ----
    float b1v[3], g1v[3], be1v[3];
#pragma unroll
    for (int n = 0; n < 3; ++n) {
        int cc = n * 16 + c16;
        bool vld = cc < 47;
        b1v[n]  = vld ? b1[cc]  : 0.f;
        g1v[n]  = vld ? g1[cc]  : 0.f;
        be1v[n] = vld ? be1[cc] : 0.f;
    }
    float b2v[8];
    f16x2 g2pk[4], be2pk[4];   // packed pairs: channels (2h)*16+c16, (2h+1)*16+c16
#pragma unroll
    for (int n = 0; n < 8; ++n) b2v[n] = b2[n * 16 + c16];
#pragma unroll
    for (int h = 0; h < 4; ++h) {
        g2pk[h][0]  = (_Float16)g2[(2 * h) * 16 + c16];
        g2pk[h][1]  = (_Float16)g2[(2 * h + 1) * 16 + c16];
        be2pk[h][0] = (_Float16)be2[(2 * h) * 16 + c16];
        be2pk[h][1] = (_Float16)be2[(2 * h + 1) * 16 + c16];
    }
    __syncthreads();

    // gather lane roles
    const int xr = lane >> 2;            // x: row within wave's 16 edges
    const int xc = (lane & 3) * 8;       //    8 channels per lane
    const int eg = lane / 11, ec = lane - eg * 11;   // ea: lanes<44
    const bool ea_act  = lane < 44;
    const bool geo_act = lane < 48;

    const int tbeg = blockIdx.x * tilesPerBlock;
    int tend = tbeg + tilesPerBlock;
    if (tend > ntiles) tend = ntiles;
    if (tbeg >= tend) return;

    // ---- cross-tile prefetch state: NAMED SCALARS ONLY (r5 lesson) ----
    int   pf_sx = 0;                     // rec[base+xr].x         (x role)
    int   pf_e0 = -1, pf_e1 = -1, pf_e2 = -1, pf_e3 = -1;   // rec[..].y (ea role)
    int   pf_gs = 0,  pf_gd = -1;        // rec[pg].x, rec[pg].z   (geo role)
    float pf_ea0 = 0.f, pf_ea1 = 0.f, pf_ea2 = 0.f, pf_ea3 = 0.f;

    // prologue: level-1 indices + ea values for the first tile
    {
        const int b2 = tbeg * 128 + row0;
        int p = b2 + xr;
        pf_sx = (p < E) ? rec[p].x : 0;
        if (ea_act) {
            int p0 = b2 + eg, p1 = b2 + 4 + eg, p2 = b2 + 8 + eg, p3 = b2 + 12 + eg;
            pf_e0 = (p0 < E) ? rec[p0].y : -1;
            pf_e1 = (p1 < E) ? rec[p1].y : -1;
            pf_e2 = (p2 < E) ? rec[p2].y : -1;
            pf_e3 = (p3 < E) ? rec[p3].y : -1;
            pf_ea0 = (pf_e0 >= 0) ? ea[(size_t)pf_e0 * 11 + ec] : 0.f;
            pf_ea1 = (pf_e1 >= 0) ? ea[(size_t)pf_e1 * 11 + ec] : 0.f;
            pf_ea2 = (pf_e2 >= 0) ? ea[(size_t)pf_e2 * 11 + ec] : 0.f;
            pf_ea3 = (pf_e3 >= 0) ? ea[(size_t)pf_e3 * 11 + ec] : 0.f;
        }
        if (geo_act) {
            int pg = b2 + c16;
            if (pg < E) {
                int3 rg = rec[pg];
                pf_gs = rg.x;
                pf_gd = rg.z;
            } else {
                pf_gs = 0; pf_gd = -1;
            }
        }
    }

    for (int tile = tbeg; tile < tend; ++tile) {
        const int base = tile * 128 + row0;   // this wave's 16 CSR positions
        const bool more = (tile + 1 < tend);

        // consume prefetched state for THIS tile
        const int   c_sx  = pf_sx;
        const int   c_gs  = pf_gs;
        const int   c_gd  = pf_gd;
        const float cea0 = pf_ea0, cea1 = pf_ea1, cea2 = pf_ea2, cea3 = pf_ea3;

        // issue level-1 prefetch for tile+1 (hidden under this whole window)
        if (more) {
            const int b2 = base + 128;
            int p = b2 + xr;
            pf_sx = (p < E) ? rec[p].x : 0;
            if (ea_act) {
                int p0 = b2 + eg, p1 = b2 + 4 + eg, p2 = b2 + 8 + eg, p3 = b2 + 12 + eg;
                pf_e0 = (p0 < E) ? rec[p0].y : -1;
                pf_e1 = (p1 < E) ? rec[p1].y : -1;
                pf_e2 = (p2 < E) ? rec[p2].y : -1;
                pf_e3 = (p3 < E) ? rec[p3].y : -1;
            }
            if (geo_act) {
                int pg = b2 + c16;
                if (pg < E) {
                    int3 rg = rec[pg];
                    pf_gs = rg.x;
                    pf_gd = rg.z;
                } else {
                    pf_gs = 0; pf_gd = -1;
                }
            }
        }

        // ---- Phase 1: second-level gathers (x, pos, nrm) + commit ----
        {
            int p = base + xr;
            bool vx = p < E;
            const float4* xp = (const float4*)(x + (size_t)c_sx * 32 + xc);
            float4 xa = xp[0];
            float4 xb = xp[1];

            float gpix = 0.f, gpiy = 0.f, gpiz = 0.f;
            float gpjx = 0.f, gpjy = 0.f, gpjz = 0.f;
            float gnix = 0.f, gniy = 0.f, gniz = 0.f;
            float gnjx = 0.f, gnjy = 0.f, gnjz = 0.f;
            if (geo_act) {
                int d2 = (c_gd < 0) ? 0 : c_gd;
                gpix = pos[d2 * 3 + 0]; gpiy = pos[d2 * 3 + 1]; gpiz = pos[d2 * 3 + 2];
                gpjx = pos[c_gs * 3 + 0]; gpjy = pos[c_gs * 3 + 1]; gpjz = pos[c_gs * 3 + 2];
                gnix = nrm[d2 * 3 + 0]; gniy = nrm[d2 * 3 + 1]; gniz = nrm[d2 * 3 + 2];
                gnjx = nrm[c_gs * 3 + 0]; gnjy = nrm[c_gs * 3 + 1]; gnjz = nrm[c_gs * 3 + 2];
            }

            // commit x
            {
                int r = row0 + xr;
                f16x8 hv;
                hv[0] = (_Float16)(vx ? xa.x : 0.f); hv[1] = (_Float16)(vx ? xa.y : 0.f);
                hv[2] = (_Float16)(vx ? xa.z : 0.f); hv[3] = (_Float16)(vx ? xa.w : 0.f);
                hv[4] = (_Float16)(vx ? xb.x : 0.f); hv[5] = (_Float16)(vx ? xb.y : 0.f);
                hv[6] = (_Float16)(vx ? xb.z : 0.f); hv[7] = (_Float16)(vx ? xb.w : 0.f);
                *(f16x8*)&msgA[r][swz(r, xc)] = hv;
            }
            // commit ea (values prefetched last iteration; invalid already 0)
            if (ea_act) {
                int r0 = row0 + 0 * 4 + eg; msgA[r0][swz(r0, 36 + ec)] = (_Float16)cea0;
                int r1 = row0 + 1 * 4 + eg; msgA[r1][swz(r1, 36 + ec)] = (_Float16)cea1;
                int r2 = row0 + 2 * 4 + eg; msgA[r2][swz(r2, 36 + ec)] = (_Float16)cea2;
                int r3 = row0 + 3 * 4 + eg; msgA[r3][swz(r3, 36 + ec)] = (_Float16)cea3;
            }
            // commit geometry (angle g per lane group)
            if (geo_act) {
                int r = row0 + c16;
                float px = gpjx - gpix, py = gpjy - gpiy, pz = gpjz - gpiz;
                float v1x, v1y, v1z, v2x, v2y, v2z;
                if (g == 0)      { v1x = gnix; v1y = gniy; v1z = gniz; v2x = px;   v2y = py;   v2z = pz; }
                else if (g == 1) { v1x = gnjx; v1y = gnjy; v1z = gnjz; v2x = px;   v2y = py;   v2z = pz; }
                else             { v1x = gnix; v1y = gniy; v1z = gniz; v2x = gnjx; v2y = gnjy; v2z = gnjz; }
                float cx = v1y * v2z - v1z * v2y;
                float cy = v1z * v2x - v1x * v2z;
                float cz = v1x * v2y - v1y * v2x;
                float ang = atan2f(sqrtf(cx * cx + cy * cy + cz * cz),
                                   v1x * v2x + v1y * v2y + v1z * v2z);
                msgA[r][swz(r, 33 + g)] = (_Float16)ang;
                if (g == 0) {
                    msgA[r][swz(r, 32)] = (_Float16)sqrtf(px * px + py * py + pz * pz);
                    dstL[r] = c_gd;
                }
            }
        }
        // no barrier: all LDS rows above are wave-private

        // ---- Phase 2: GEMM1 (16x48) + LN1 -> h1 back into msgA ----
        f32x4 acc1[3];
#pragma unroll
        for (int n = 0; n < 3; ++n) acc1[n] = (f32x4){0.f, 0.f, 0.f, 0.f};
#pragma unroll
        for (int ks = 0; ks < 2; ++ks) {
            int ar = row0 + c16;
            f16x8 a = *(const f16x8*)&msgA[ar][swz(ar, ks * 32 + g * 8)];
#pragma unroll
            for (int n = 0; n < 3; ++n) {
                int br = n * 16 + c16;
                f16x8 b = *(const f16x8*)&W1t[br][swz(br, ks * 32 + g * 8)];
                acc1[n] = __builtin_amdgcn_mfma_f32_16x16x32_f16(a, b, acc1[n], 0, 0, 0);
            }
        }
#pragma unroll
        for (int q = 0; q < 4; ++q) {
            float t0 = fmaxf(acc1[0][q] + b1v[0], 0.f);
            float t1 = fmaxf(acc1[1][q] + b1v[1], 0.f);
            float t2 = fmaxf(acc1[2][q] + b1v[2], 0.f);   // col 47 -> 0
            float s = t0 + t1 + t2;
            float s2 = t0 * t0 + t1 * t1 + t2 * t2;
#pragma unroll
            for (int m = 1; m < 16; m <<= 1) {
                s  += __shfl_xor(s,  m, 64);
                s2 += __shfl_xor(s2, m, 64);
            }
            float mu  = s * (1.f / 47.f);
            float var = s2 * (1.f / 47.f) - mu * mu;
            float rs  = rsqrtf(var + 1e-5f);
            int r = row0 + 4 * g + q;
            msgA[r][swz(r, c16)]      = (_Float16)((t0 - mu) * rs * g1v[0] + be1v[0]);
            msgA[r][swz(r, 16 + c16)] = (_Float16)((t1 - mu) * rs * g1v[1] + be1v[1]);
            msgA[r][swz(r, 32 + c16)] = (_Float16)((t2 - mu) * rs * g1v[2] + be1v[2]);
        }

        // issue level-2 ea prefetch for tile+1 (level-1 loads returned by now;
        // hidden under GEMM2 + LN2 + walk)
        if (more && ea_act) {
            pf_ea0 = (pf_e0 >= 0) ? ea[(size_t)pf_e0 * 11 + ec] : 0.f;
            pf_ea1 = (pf_e1 >= 0) ? ea[(size_t)pf_e1 * 11 + ec] : 0.f;
            pf_ea2 = (pf_e2 >= 0) ? ea[(size_t)pf_e2 * 11 + ec] : 0.f;
            pf_ea3 = (pf_e3 >= 0) ? ea[(size_t)pf_e3 * 11 + ec] : 0.f;
        }

        // ---- Phase 3: GEMM2 (16x128) + LN2 (packed-f16 apply) -> h2w ----
        f32x4 acc2[8];
#pragma unroll
        for (int n = 0; n < 8; ++n) acc2[n] = (f32x4){0.f, 0.f, 0.f, 0.f};
#pragma unroll
        for (int ks = 0; ks < 2; ++ks) {
            int ar = row0 + c16;
            f16x8 a = *(const f16x8*)&msgA[ar][swz(ar, ks * 32 + g * 8)];
#pragma unroll
            for (int n = 0; n < 8; ++n) {
                int br = n * 16 + c16;
                f16x8 b = *(const f16x8*)&W2t[br][swz(br, ks * 32 + g * 8)];
                acc2[n] = __builtin_amdgcn_mfma_f32_16x16x32_f16(a, b, acc2[n], 0, 0, 0);
            }
        }
#pragma unroll
        for (int q = 0; q < 4; ++q) {
            float t[8];
            float s = 0.f, s2 = 0.f;
#pragma unroll
            for (int n = 0; n < 8; ++n) {
                t[n] = fmaxf(acc2[n][q] + b2v[n], 0.f);
                s += t[n]; s2 += t[n] * t[n];
            }
#pragma unroll
            for (int m = 1; m < 16; m <<= 1) {
                s  += __shfl_xor(s,  m, 64);
                s2 += __shfl_xor(s2, m, 64);
            }
            float mu  = s * (1.f / 128.f);
            float var = s2 * (1.f / 128.f) - mu * mu;
            float rs  = rsqrtf(var + 1e-5f);
            int r = row0 + 4 * g + q;
            // packed apply: h = (t*rs - mu*rs)*gamma + beta, two v_pk_fma_f16
            f16x2 apk = pkrtz(rs, rs);
            f16x2 cpk = pkrtz(-mu * rs, -mu * rs);
#pragma unroll
            for (int h = 0; h < 4; ++h) {
                f16x2 tpk = pkrtz(t[2 * h], t[2 * h + 1]);
                f16x2 z   = tpk * apk + cpk;
                f16x2 hvp = z * g2pk[h] + be2pk[h];
                h2w[r][(2 * h) * 16 + c16]     = hvp[0];
                h2w[r][(2 * h + 1) * 16 + c16] = hvp[1];
            }
        }

        // ---- Phase 4: segmented max walk (f16 max; decode at emit only) ----
        {
            f16x2 mneg; mneg[0] = mneg[1] = (_Float16)(-65504.f);
            f16x2 mx = mneg;
            int segStart = 0;
            int dcur = dstL[row0];
#pragma unroll
            for (int r = 0; r < 16; ++r) {
                f16x2 pk = *(const f16x2*)&h2w[row0 + r][lane * 2];
                mx[0] = (pk[0] > mx[0]) ? pk[0] : mx[0];
                mx[1] = (pk[1] > mx[1]) ? pk[1] : mx[1];
                int dnext = (r < 15) ? dstL[row0 + r + 1] : -2;
                if (dnext != dcur) {
                    if (dcur >= 0) {
                        unsigned e0 = fenc((float)mx[0]);
                        unsigned e1 = fenc((float)mx[1]);
                        unsigned* orow = out + (size_t)dcur * 128 + lane * 2;
                        if (segStart > 0 && r < 15) {
                            unsigned long long pk2 =
                                ((unsigned long long)e1 << 32) | (unsigned long long)e0;
                            *(unsigned long long*)orow = pk2;
                        } else {
                            atomicMax(orow,     e0);
                            atomicMax(orow + 1, e1);
                        }
                    }
                    mx = mneg;
                    segStart = r + 1; dcur = dnext;
                }
            }
        }
    }
}

// ---------------- fallback: direct atomics, no CSR (round-2 form) ----------------
#define LDKF 72
__global__ __launch_bounds__(256) void edge_kernel_atomic(
    const float* __restrict__ x,   const float* __restrict__ pos,
    const float* __restrict__ nrm, const float* __restrict__ ea,
    const float* __restrict__ W1,  const float* __restrict__ b1,
    const float* __restrict__ g1,  const float* __restrict__ be1,
    const float* __restrict__ W2,  const float* __restrict__ b2,
    const float* __restrict__ g2,  const float* __restrict__ be2,
    const int* __restrict__ srcI,  const int* __restrict__ dstI,
    unsigned* __restrict__ out, int E, int ntiles)
{
    __shared__ _Float16 W1t[48][LDKF];
    __shared__ _Float16 W2t[128][LDKF];
    __shared__ _Float16 msgA[64][LDKF];
    __shared__ int dst_s[64];

    const int lane = threadIdx.x & 63;
    const int w    = threadIdx.x >> 6;
    const int c16  = lane & 15;
    const int g    = lane >> 4;

    for (int i = threadIdx.x; i < 48 * 64; i += 256) {
        int n = i >> 6, k = i & 63;
        W1t[n][k] = (n < 47 && k < 47) ? (_Float16)W1[k * 47 + n] : (_Float16)0.f;
    }
    for (int i = threadIdx.x; i < 128 * 64; i += 256) {
        int n = i >> 6, k = i & 63;
        W2t[n][k] = (k < 47) ? (_Float16)W2[k * 128 + n] : (_Float16)0.f;
    }
    for (int i = threadIdx.x; i < 64 * LDKF; i += 256)
        (&msgA[0][0])[i] = (_Float16)0.f;

    float b1v[3], g1v[3], be1v[3];
#pragma unroll
    for (int n = 0; n < 3; ++n) {
        int cc = n * 16 + c16;
        bool vld = cc < 47;
        b1v[n]  = vld ? b1[cc]  : 0.f;
        g1v[n]  = vld ? g1[cc]  : 0.f;
        be1v[n] = vld ? be1[cc] : 0.f;
    }
    float b2v[8], g2v[8], be2v[8];
#pragma unroll
    for (int n = 0; n < 8; ++n) {
        int cc = n * 16 + c16;
        b2v[n] = b2[cc]; g2v[n] = g2[cc]; be2v[n] = be2[cc];
    }
    __syncthreads();

    for (int tile = blockIdx.x; tile < ntiles; tile += gridDim.x) {
        const int base = tile * 64 + w * 16;
        const int row0 = w * 16;
#pragma unroll
        for (int i = 0; i < 8; ++i) {
            int el = i * 2 + (lane >> 5);
            int e  = base + el;
            int c  = lane & 31;
            float v = 0.f;
            if (e < E) v = x[(size_t)srcI[e] * 32 + c];
            msgA[row0 + el][c] = (_Float16)v;
        }
        if (lane < 44) {
            int eg = lane / 11, c = lane - eg * 11;
#pragma unroll
            for (int i = 0; i < 4; ++i) {
                int el = i * 4 + eg;
                int e  = base + el;
                float v = 0.f;
                if (e < E) v = ea[(size_t)e * 11 + c];
                msgA[row0 + el][36 + c] = (_Float16)v;
            }
        }
        if (lane < 48) {
            int el = c16;
            int e  = base + el;
            int s = 0, d = 0;
            bool vld = e < E;
            if (vld) { s = srcI[e]; d = dstI[e]; }
            float pix = pos[d * 3 + 0], piy = pos[d * 3 + 1], piz = pos[d * 3 + 2];
            float pjx = pos[s * 3 + 0], pjy = pos[s * 3 + 1], pjz = pos[s * 3 + 2];
            float nix = nrm[d * 3 + 0], niy = nrm[d * 3 + 1], niz = nrm[d * 3 + 2];
            float njx = nrm[s * 3 + 0], njy = nrm[s * 3 + 1], njz = nrm[s * 3 + 2];
            float px = pjx - pix, py = pjy - piy, pz = pjz - piz;
            float v1x, v1y, v1z, v2x, v2y, v2z;
            if (g == 0)      { v1x = nix; v1y = niy; v1z = niz; v2x = px;  v2y = py;  v2z = pz;  }
            else if (g == 1) { v1x = njx; v1y = njy; v1z = njz; v2x = px;  v2y = py;  v2z = pz;  }
            else             { v1x = nix; v1y = niy; v1z = niz; v2x = njx; v2y = njy; v2z = njz; }
            float cx = v1y * v2z - v1z * v2y;
            float cy = v1z * v2x - v1x * v2z;
            float cz = v1x * v2y - v1y * v2x;
            float ang = atan2f(sqrtf(cx * cx + cy * cy + cz * cz),
                               v1x * v2x + v1y * v2y + v1z * v2z);
            msgA[row0 + el][33 + g] = (_Float16)ang;
            if (g == 0) {
                msgA[row0 + el][32] = (_Float16)sqrtf(px * px + py * py + pz * pz);
                dst_s[row0 + el] = vld ? d : -1;
            }
        }

        f32x4 acc1[3];
#pragma unroll
        for (int n = 0; n < 3; ++n) acc1[n] = (f32x4){0.f, 0.f, 0.f, 0.f};
#pragma unroll
        for (int ks = 0; ks < 2; ++ks) {
            f16x8 a = *(const f16x8*)&msgA[row0 + c16][ks * 32 + g * 8];
#pragma unroll
            for (int n = 0; n < 3; ++n) {
                f16x8 b = *(const f16x8*)&W1t[n * 16 + c16][ks * 32 + g * 8];
                acc1[n] = __builtin_amdgcn_mfma_f32_16x16x32_f16(a, b, acc1[n], 0, 0, 0);
            }
        }
#pragma unroll
        for (int q = 0; q < 4; ++q) {
            float t0 = fmaxf(acc1[0][q] + b1v[0], 0.f);
            float t1 = fmaxf(acc1[1][q] + b1v[1], 0.f);
            float t2 = fmaxf(acc1[2][q] + b1v[2], 0.f);
            float s = t0 + t1 + t2;
            float s2 = t0 * t0 + t1 * t1 + t2 * t2;
#pragma unroll
            for (int m = 1; m < 16; m <<= 1) {
                s  += __shfl_xor(s,  m, 64);
                s2 += __shfl_xor(s2, m, 64);
            }
            float mu  = s * (1.f / 47.f);
            float var = s2 * (1.f / 47.f) - mu * mu;
            float rs  = rsqrtf(var + 1e-5f);
            int r = row0 + 4 * g + q;
            msgA[r][c16]      = (_Float16)((t0 - mu) * rs * g1v[0] + be1v[0]);
            msgA[r][16 + c16] = (_Float16)((t1 - mu) * rs * g1v[1] + be1v[1]);
            msgA[r][32 + c16] = (_Float16)((t2 - mu) * rs * g1v[2] + be1v[2]);
        }

        f32x4 acc2[8];
#pragma unroll
        for (int n = 0; n < 8; ++n) acc2[n] = (f32x4){0.f, 0.f, 0.f, 0.f};
#pragma unroll
        for (int ks = 0; ks < 2; ++ks) {
            f16x8 a = *(const f16x8*)&msgA[row0 + c16][ks * 32 + g * 8];
#pragma unroll
            for (int n = 0; n < 8; ++n) {
                f16x8 b = *(const f16x8*)&W2t[n * 16 + c16][ks * 32 + g * 8];
                acc2[n] = __builtin_amdgcn_mfma_f32_16x16x32_f16(a, b, acc2[n], 0, 0, 0);
            }
        }
        int4 dd = *(const int4*)&dst_s[row0 + 4 * g];
#pragma unroll
        for (int q = 0; q < 4; ++q) {
            float t[8];
            float s = 0.f, s2 = 0.f;
#pragma unroll
            for (int n = 0; n < 8; ++n) {
                t[n] = fmaxf(acc2[n][q] + b2v[n], 0.f);
                s += t[n]; s2 += t[n] * t[n];
            }
#pragma unroll
            for (int m = 1; m < 16; m <<= 1) {
                s  += __shfl_xor(s,  m, 64);
                s2 += __shfl_xor(s2, m, 64);
            }
            float mu  = s * (1.f / 128.f);
            float var = s2 * (1.f / 128.f) - mu * mu;
            float rs  = rsqrtf(var + 1e-5f);
            int d = (&dd.x)[q];
            if (d >= 0) {
                unsigned* orow = out + (size_t)d * 128u;
#pragma unroll
                for (int n = 0; n < 8; ++n) {
                    float o = (t[n] - mu) * rs * g2v[n] + be2v[n];
                    atomicMax(orow + n * 16 + c16, fenc(o));
                }
            }
        }
    }
}

extern "C" void kernel_launch(void* const* d_in, const int* in_sizes, int n_in,
                              void* d_out, int out_size, void* d_ws, size_t ws_size,
                              hipStream_t stream) {
    const float* x   = (const float*)d_in[0];
    const float* pos = (const float*)d_in[1];
    const float* nrm = (const float*)d_in[2];
    const float* ea  = (const float*)d_in[3];
    const float* W1  = (const float*)d_in[4];
    const float* b1  = (const float*)d_in[5];
    const float* g1  = (const float*)d_in[6];
    const float* be1 = (const float*)d_in[7];
    const float* W2  = (const float*)d_in[8];
    const float* b2  = (const float*)d_in[9];
    const float* g2  = (const float*)d_in[10];
    const float* be2 = (const float*)d_in[11];
    const int*   idx = (const int*)d_in[12];

    const int N = in_sizes[0] / 32;
    const int E = in_sizes[3] / 11;
    const int* srcI = idx;
    const int* dstI = idx + E;

    unsigned* outU = (unsigned*)d_out;
    const int n = N * 128;

    init_out_kernel<<<(n / 4 + 255) / 256, 256, 0, stream>>>(outU, n / 4);

    const int nb = (N + 1023) / 1024;
    // ws layout: rec[E] int3 (12B) | counts[N] | nextp[N] | bsums[nb]
    const size_t needed = (size_t)E * 12 + (size_t)(2LL * N + nb) * 4;

    if (ws_size >= needed) {
        int3* rec    = (int3*)d_ws;
        int*  counts = (int*)(rec + E);
        int*  nextp  = counts + N;
        int*  bsums  = nextp + N;

        hipMemsetAsync(counts, 0, (size_t)N * 4, stream);
        hist_kernel<<<(E + 255) / 256, 256, 0, stream>>>(dstI, counts, E);
        scan_blk<<<nb, 1024, 0, stream>>>(counts, nextp, bsums, N);
        scan_blk<<<1, 1024, 0, stream>>>(bsums, bsums, (int*)nullptr, nb);
        scatter_kernel<<<(E + 255) / 256, 256, 0, stream>>>(srcI, dstI, nextp, bsums,
                                                            rec, E);

        const int ntiles = (E + 127) / 128;
        int grid = ntiles < 512 ? ntiles : 512;    // 2 blocks/CU resident, persistent
        int tpb  = (ntiles + grid - 1) / grid;
        edge_kernel_csr<<<grid, 512, 0, stream>>>(x, pos, nrm, ea,
                                                  W1, b1, g1, be1,
                                                  W2, b2, g2, be2,
                                                  rec,
                                                  outU, E, ntiles, tpb);
    } else {
        const int ntiles = (E + 63) / 64;
        int grid = ntiles < 4096 ? ntiles : 4096;
        edge_kernel_atomic<<<grid, 256, 0, stream>>>(x, pos, nrm, ea,
                                                     W1, b1, g1, be1,
                                                     W2, b2, g2, be2,
                                                     srcI, dstI, outU, E, ntiles);
    }

    finalize_out_kernel<<<(n / 4 + 255) / 256, 256, 0, stream>>>((float*)d_out, n / 4);
}